// Round 1
// baseline (369.351 us; speedup 1.0000x reference)
//
#include <hip/hip_runtime.h>
#include <hip/hip_bf16.h>

// Problem: x[128][768][28][28] f32 -> per-(b,c) k-th order statistic
// (ascending index N-k = 392 of N=784), then med[128][768] @ W[1000][768]^T + b.

#define NROW 784          // 28*28
#define RANK_IDX 392      // N - N//2
#define BDIM 256

// ---------------- Kernel 1: exact order statistic via 4x8-bit radix select ----
__global__ __launch_bounds__(BDIM) void kth_select_kernel(
    const float* __restrict__ x, float* __restrict__ med) {
  __shared__ unsigned keys[NROW];
  __shared__ unsigned hist[256];
  __shared__ unsigned waveSum[4];
  __shared__ unsigned s_prefix, s_rank;

  const int row = blockIdx.x;                 // 0 .. 128*768-1
  const float* src = x + (size_t)row * NROW;  // row base, 16B aligned (784*4)
  const int tid = threadIdx.x;

  // Load 784 floats as 196 float4, convert to monotone-sortable u32 keys.
  if (tid < 196) {
    float4 v = ((const float4*)src)[tid];
    float vv[4] = {v.x, v.y, v.z, v.w};
#pragma unroll
    for (int j = 0; j < 4; ++j) {
      unsigned bts = __float_as_uint(vv[j]);
      keys[tid * 4 + j] = (bts & 0x80000000u) ? ~bts : (bts | 0x80000000u);
    }
  }
  __syncthreads();

  unsigned prefix = 0;
  unsigned r = RANK_IDX;

#pragma unroll
  for (int pass = 0; pass < 4; ++pass) {
    const int shift = 24 - 8 * pass;
    const unsigned hmask = (pass == 0) ? 0u : (0xFFFFFFFFu << (shift + 8));

    hist[tid] = 0;
    __syncthreads();  // (A)

    // Histogram of current 8-bit digit among elements matching prefix.
#pragma unroll
    for (int i = tid; i < NROW; i += BDIM) {
      unsigned kk = keys[i];
      if ((kk & hmask) == prefix)
        atomicAdd(&hist[(kk >> shift) & 255u], 1u);
    }
    __syncthreads();  // (B)

    // Block-wide inclusive scan over 256 bins (thread t owns bin t).
    unsigned v = hist[tid];
    unsigned incl = v;
#pragma unroll
    for (int off = 1; off < 64; off <<= 1) {
      unsigned n = __shfl_up(incl, off, 64);
      if ((tid & 63) >= off) incl += n;
    }
    const int wave = tid >> 6;
    if ((tid & 63) == 63) waveSum[wave] = incl;
    __syncthreads();  // (C)
    unsigned base = 0;
    for (int w = 0; w < wave; ++w) base += waveSum[w];
    incl += base;
    const unsigned excl = incl - v;

    if (v > 0 && excl <= r && r < incl) {   // exactly one thread wins
      s_prefix = prefix | ((unsigned)tid << shift);
      s_rank = r - excl;
    }
    __syncthreads();  // (D)
    prefix = s_prefix;
    r = s_rank;
    __syncthreads();  // protect s_* / hist before next pass writes
  }

  if (tid == 0) {
    // prefix is the full sortable key of the selected element; invert mapping.
    unsigned bts = (prefix & 0x80000000u) ? (prefix & 0x7fffffffu) : ~prefix;
    med[row] = __uint_as_float(bts);
  }
}

// ---------------- Kernel 2: small f32 GEMM out = med @ W^T + bias ------------
// out[128][1000], med[128][768], W[1000][768] row-major.
#define GO 32   // o-tile
#define GB 16   // b-tile
#define GK 64   // k-tile

__global__ __launch_bounds__(BDIM) void gemm_kernel(
    const float* __restrict__ med, const float* __restrict__ W,
    const float* __restrict__ bias, float* __restrict__ out) {
  __shared__ float Ws[GK][GO + 1];  // stored transposed: [kc][ol]; 33%32==1 -> conflict-free
  __shared__ float Ms[GB][GK];

  const int o0 = blockIdx.x * GO;
  const int b0 = blockIdx.y * GB;
  const int tid = threadIdx.x;
  const int to = tid & 31;   // o within tile
  const int tb = tid >> 5;   // 0..7 -> 2 b's each

  float acc0 = 0.f, acc1 = 0.f;

  for (int k0 = 0; k0 < 768; k0 += GK) {
    // Stage W tile (32 o x 64 k), coalesced rows, transposed store.
#pragma unroll
    for (int idx = tid; idx < GO * GK; idx += BDIM) {
      const int kc = idx & (GK - 1);
      const int ol = idx >> 6;
      const int o = o0 + ol;
      Ws[kc][ol] = (o < 1000) ? W[(size_t)o * 768 + k0 + kc] : 0.f;
    }
    // Stage med tile (16 b x 64 k).
#pragma unroll
    for (int idx = tid; idx < GB * GK; idx += BDIM) {
      const int kc = idx & (GK - 1);
      const int bl = idx >> 6;
      Ms[bl][kc] = med[(size_t)(b0 + bl) * 768 + k0 + kc];
    }
    __syncthreads();

    const int bl = tb * 2;
#pragma unroll
    for (int k = 0; k < GK; ++k) {
      const float wv = Ws[k][to];      // broadcast pairs, conflict-free
      acc0 = fmaf(Ms[bl][k], wv, acc0);
      acc1 = fmaf(Ms[bl + 1][k], wv, acc1);
    }
    __syncthreads();
  }

  const int o = o0 + to;
  if (o < 1000) {
    const float bb = bias[o];
    const int b = b0 + tb * 2;
    out[(size_t)b * 1000 + o] = acc0 + bb;
    out[(size_t)(b + 1) * 1000 + o] = acc1 + bb;
  }
}

extern "C" void kernel_launch(void* const* d_in, const int* in_sizes, int n_in,
                              void* d_out, int out_size, void* d_ws, size_t ws_size,
                              hipStream_t stream) {
  const float* x = (const float*)d_in[0];    // [128,768,28,28]
  const float* W = (const float*)d_in[1];    // [1000,768]
  const float* b = (const float*)d_in[2];    // [1000]
  float* out = (float*)d_out;                // [128,1000]
  float* med = (float*)d_ws;                 // [128,768] scratch (393 KB)

  const int rows = 128 * 768;
  kth_select_kernel<<<rows, BDIM, 0, stream>>>(x, med);

  dim3 grid((1000 + GO - 1) / GO, 128 / GB);
  gemm_kernel<<<grid, BDIM, 0, stream>>>(med, W, b, out);
}

// Round 2
// 169.731 us; speedup vs baseline: 2.1761x; 2.1761x over previous
//
#include <hip/hip_runtime.h>
#include <hip/hip_bf16.h>

// x[128][768][28][28] f32 -> per-(b,c) ascending-rank-392 of 784 values,
// then med[128][768] @ W[1000][768]^T + bias -> out[128][1000].

#define NROW 784
#define RANKK 392u
#define NWAVE 4   // rows (waves) per block

// ---------------- Kernel 1: per-wave exact radix select -----------------------
// One 64-lane wave owns one row. No __syncthreads anywhere (wave-order LDS).
// Pass 1: 64-bin histogram of top-6 key bits computed from REGISTERS
// (4 bank-staggered sub-histograms to tame same-digit atomic serialization),
// winning bucket compacted to LDS. Then <=5 tiny 6-bit refinement passes
// (in-place compaction), then O(m) count-less-than finisher.
__global__ __launch_bounds__(256) void kth_select_kernel(
    const float* __restrict__ x, float* __restrict__ med) {
  __shared__ unsigned cand[NWAVE][NROW];     // 12544 B
  __shared__ unsigned hist[NWAVE][4][65];    // 4160 B, stride 65 staggers banks

  const int tid  = threadIdx.x;
  const int lane = tid & 63;
  const int w    = tid >> 6;
  const int row  = blockIdx.x * NWAVE + w;
  const float4* src4 = (const float4*)(x + (size_t)row * NROW);
  const unsigned long long ltm = (1ull << lane) - 1ull;
  const int sub = lane & 3;

  // ---- load row: lane gets float4 indices {lane, 64+lane, 128+lane, 192+lane(lane<4)}
  float4 f0 = src4[lane];
  float4 f1 = src4[64 + lane];
  float4 f2 = src4[128 + lane];
  const bool v3 = (lane < 4);
  float4 f3 = make_float4(0.f, 0.f, 0.f, 0.f);
  if (v3) f3 = src4[192 + lane];

  // ---- convert to monotone-sortable u32 keys (registers only)
  unsigned k[16];
  {
    const float vv[16] = {f0.x, f0.y, f0.z, f0.w, f1.x, f1.y, f1.z, f1.w,
                          f2.x, f2.y, f2.z, f2.w, f3.x, f3.y, f3.z, f3.w};
#pragma unroll
    for (int j = 0; j < 16; ++j) {
      unsigned b = __float_as_uint(vv[j]);
      k[j] = (b & 0x80000000u) ? ~b : (b | 0x80000000u);
    }
  }

  // ---- pass 1 histogram (digit = key>>26), from registers
#pragma unroll
  for (int s = 0; s < 4; ++s) hist[w][s][lane] = 0u;
#pragma unroll
  for (int j = 0; j < 12; ++j) atomicAdd(&hist[w][sub][k[j] >> 26], 1u);
  if (v3) {
#pragma unroll
    for (int j = 12; j < 16; ++j) atomicAdd(&hist[w][sub][k[j] >> 26], 1u);
  }

  unsigned r = RANKK;
  unsigned m;
  int D;
  {
    unsigned cnt = hist[w][0][lane] + hist[w][1][lane] + hist[w][2][lane] + hist[w][3][lane];
    unsigned incl = cnt;
#pragma unroll
    for (int off = 1; off < 64; off <<= 1) {
      unsigned t = __shfl_up(incl, off, 64);
      if (lane >= off) incl += t;
    }
    const unsigned excl = incl - cnt;
    const bool hit = (r >= excl) && (r < incl);
    const unsigned long long hm = __ballot(hit);
    D = __ffsll(hm) - 1;                 // winning digit == lane index
    r -= __shfl(excl, D, 64);
    m  = __shfl(cnt,  D, 64);
  }

  // ---- compact winning-bucket keys from registers into cand[w][0..m-1]
  {
    unsigned base = 0;
#pragma unroll
    for (int j = 0; j < 16; ++j) {
      const bool va = (j < 12) || v3;
      const bool match = va && ((int)(k[j] >> 26) == D);
      const unsigned long long mk = __ballot(match);
      if (match) cand[w][base + (unsigned)__popcll(mk & ltm)] = k[j];
      base += (unsigned)__popcll(mk);
    }
  }

  // ---- refinement passes over LDS candidates (in-place compaction)
#pragma unroll 1
  for (int p = 0; p < 5; ++p) {
    if (m <= 64u) break;
    const int shift = (p < 4) ? (20 - 6 * p) : 0;
#pragma unroll
    for (int s = 0; s < 4; ++s) hist[w][s][lane] = 0u;
    const int nch = (int)((m + 63u) >> 6);
    for (int c = 0; c < nch; ++c) {
      const int idx = (c << 6) + lane;
      if (idx < (int)m) atomicAdd(&hist[w][sub][(cand[w][idx] >> shift) & 63u], 1u);
    }
    unsigned cnt = hist[w][0][lane] + hist[w][1][lane] + hist[w][2][lane] + hist[w][3][lane];
    unsigned incl = cnt;
#pragma unroll
    for (int off = 1; off < 64; off <<= 1) {
      unsigned t = __shfl_up(incl, off, 64);
      if (lane >= off) incl += t;
    }
    const unsigned excl = incl - cnt;
    const bool hit = (r >= excl) && (r < incl);
    const unsigned long long hm = __ballot(hit);
    D = __ffsll(hm) - 1;
    r -= __shfl(excl, D, 64);
    const unsigned m2 = __shfl(cnt, D, 64);
    // in-place compact: dest index <= source index; wave LDS ops are in-order.
    unsigned base = 0;
    for (int c = 0; c < nch; ++c) {
      const int idx = (c << 6) + lane;
      const bool va = idx < (int)m;
      const unsigned kk = va ? cand[w][idx] : 0u;
      const bool match = va && (((kk >> shift) & 63u) == (unsigned)D);
      const unsigned long long mk = __ballot(match);
      if (match) cand[w][base + (unsigned)__popcll(mk & ltm)] = kk;
      base += (unsigned)__popcll(mk);
    }
    m = m2;
  }

  // ---- finisher
  unsigned selKey = 0;
  bool win = false;
  if (m > 64u) {
    // all remaining candidates share every digit -> identical keys
    selKey = cand[w][0];
    win = (lane == 0);
  } else {
    const unsigned myk = (lane < (int)m) ? cand[w][lane] : 0xFFFFFFFFu;
    unsigned cl = 0, ce = 0;
    for (int j = 0; j < (int)m; ++j) {
      const unsigned kj = cand[w][j];   // uniform addr -> LDS broadcast
      cl += (kj < myk) ? 1u : 0u;
      ce += (kj == myk) ? 1u : 0u;
    }
    selKey = myk;
    win = (lane < (int)m) && (cl <= r) && (r < cl + ce);
  }
  if (win) {
    const unsigned b = (selKey & 0x80000000u) ? (selKey & 0x7fffffffu) : ~selKey;
    med[row] = __uint_as_float(b);
  }
}

// ---------------- Kernel 2: small f32 GEMM out = med @ W^T + bias ------------
#define GO 32
#define GB 8
#define GK 64

__global__ __launch_bounds__(256) void gemm_kernel(
    const float* __restrict__ med, const float* __restrict__ W,
    const float* __restrict__ bias, float* __restrict__ out) {
  __shared__ float Ws[GK][GO + 1];  // [kc][ol], stride 33 -> conflict-free
  __shared__ float Ms[GB][GK];

  const int o0 = blockIdx.x * GO;
  const int b0 = blockIdx.y * GB;
  const int tid = threadIdx.x;
  const int to = tid & 31;
  const int tb = tid >> 5;

  float acc = 0.f;

  for (int k0 = 0; k0 < 768; k0 += GK) {
#pragma unroll
    for (int idx = tid; idx < GO * GK; idx += 256) {
      const int kc = idx & (GK - 1);
      const int ol = idx >> 6;
      const int o = o0 + ol;
      Ws[kc][ol] = (o < 1000) ? W[(size_t)o * 768 + k0 + kc] : 0.f;
    }
#pragma unroll
    for (int idx = tid; idx < GB * GK; idx += 256) {
      const int kc = idx & (GK - 1);
      const int bl = idx >> 6;
      Ms[bl][kc] = med[(size_t)(b0 + bl) * 768 + k0 + kc];
    }
    __syncthreads();
#pragma unroll
    for (int kk = 0; kk < GK; ++kk)
      acc = fmaf(Ms[tb][kk], Ws[kk][to], acc);
    __syncthreads();
  }

  const int o = o0 + to;
  if (o < 1000)
    out[(size_t)(b0 + tb) * 1000 + o] = acc + bias[o];
}

extern "C" void kernel_launch(void* const* d_in, const int* in_sizes, int n_in,
                              void* d_out, int out_size, void* d_ws, size_t ws_size,
                              hipStream_t stream) {
  const float* x = (const float*)d_in[0];    // [128,768,28,28]
  const float* W = (const float*)d_in[1];    // [1000,768]
  const float* b = (const float*)d_in[2];    // [1000]
  float* out = (float*)d_out;                // [128,1000]
  float* med = (float*)d_ws;                 // [128,768] scratch

  const int rows = 128 * 768;                // 98304
  kth_select_kernel<<<rows / NWAVE, 256, 0, stream>>>(x, med);

  dim3 grid((1000 + GO - 1) / GO, 128 / GB); // (32,16)
  gemm_kernel<<<grid, 256, 0, stream>>>(med, W, b, out);
}

// Round 3
// 128.043 us; speedup vs baseline: 2.8846x; 1.3256x over previous
//
#include <hip/hip_runtime.h>
#include <hip/hip_bf16.h>

// x[128][768][28][28] f32 -> per-(b,c) ascending-rank-392 of 784 values,
// then med[128][768] @ W[1000][768]^T + bias -> out[128][1000].

#define NROW 784
#define RANKK 392u
#define NWAVE 4   // rows (waves) per block

// ---------------- Kernel 1: per-wave exact select ----------------------------
// One 64-lane wave owns one row; no __syncthreads (wave-order LDS semantics).
// Pass 1 bins by the MONOTONE linear partition bucket=clamp(floor(16v)+32,0,63)
// (near-uniform for this data -> low-conflict atomics, small winning bucket),
// compacts the winning bucket, then O(m) count-less-than finisher. Exact
// MSB-radix refinement remains as fallback for m>64 (any data distribution).
__global__ __launch_bounds__(256) void kth_select_kernel(
    const float* __restrict__ x, float* __restrict__ med) {
  __shared__ unsigned cand[NWAVE][NROW];     // 12544 B
  __shared__ unsigned hist[NWAVE][4][65];    // 4160 B

  const int tid  = threadIdx.x;
  const int lane = tid & 63;
  const int w    = tid >> 6;
  const int row  = blockIdx.x * NWAVE + w;
  const float4* src4 = (const float4*)(x + (size_t)row * NROW);
  const unsigned long long ltm = (1ull << lane) - 1ull;
  const int sub = lane & 3;

  // ---- load row: 196 float4 spread as {lane, 64+lane, 128+lane, 192+lane<4}
  float4 f0 = src4[lane];
  float4 f1 = src4[64 + lane];
  float4 f2 = src4[128 + lane];
  const bool v3 = (lane < 4);
  float4 f3 = make_float4(0.f, 0.f, 0.f, 0.f);
  if (v3) f3 = src4[192 + lane];

  const float vv[16] = {f0.x, f0.y, f0.z, f0.w, f1.x, f1.y, f1.z, f1.w,
                        f2.x, f2.y, f2.z, f2.w, f3.x, f3.y, f3.z, f3.w};

  // ---- monotone linear buckets (trunc->floor via __float2int_rd; clamp safe)
  int bkt[16];
#pragma unroll
  for (int j = 0; j < 16; ++j) {
    const float t = fminf(fmaxf(vv[j] * 16.f, -40.f), 40.f);
    const int bi = __float2int_rd(t) + 32;
    bkt[j] = min(max(bi, 0), 63);
  }

  // ---- pass-1 histogram (4 bank-staggered sub-hists; wave-private, no sync)
#pragma unroll
  for (int s = 0; s < 4; ++s) hist[w][s][lane] = 0u;
#pragma unroll
  for (int j = 0; j < 12; ++j) atomicAdd(&hist[w][sub][bkt[j]], 1u);
  if (v3) {
#pragma unroll
    for (int j = 12; j < 16; ++j) atomicAdd(&hist[w][sub][bkt[j]], 1u);
  }

  unsigned r = RANKK;
  unsigned m;
  int D;
  {
    unsigned cnt = hist[w][0][lane] + hist[w][1][lane] + hist[w][2][lane] + hist[w][3][lane];
    unsigned incl = cnt;
#pragma unroll
    for (int off = 1; off < 64; off <<= 1) {
      unsigned t = __shfl_up(incl, off, 64);
      if (lane >= off) incl += t;
    }
    const unsigned excl = incl - cnt;
    const bool hit = (r >= excl) && (r < incl);
    const unsigned long long hm = __ballot(hit);
    D = __ffsll(hm) - 1;                // winning bucket == lane index
    r -= __shfl(excl, D, 64);
    m  = __shfl(cnt,  D, 64);
  }

  // ---- compact winning-bucket elements (as monotone-sortable u32 keys)
  {
    unsigned base = 0;
#pragma unroll
    for (int j = 0; j < 16; ++j) {
      const bool va = (j < 12) || v3;
      const bool match = va && (bkt[j] == D);
      const unsigned long long mk = __ballot(match);
      if (match) {
        const unsigned b = __float_as_uint(vv[j]);
        const unsigned key = (b & 0x80000000u) ? ~b : (b | 0x80000000u);
        cand[w][base + (unsigned)__popcll(mk & ltm)] = key;
      }
      base += (unsigned)__popcll(mk);
    }
  }

  // ---- fallback: exact MSB 6-bit radix refinement (only if m > 64)
#pragma unroll 1
  for (int p = 0; p < 6; ++p) {
    if (m <= 64u) break;
    const int shift = (p < 5) ? (26 - 6 * p) : 0;
#pragma unroll
    for (int s = 0; s < 4; ++s) hist[w][s][lane] = 0u;
    const int nch = (int)((m + 63u) >> 6);
    for (int c = 0; c < nch; ++c) {
      const int idx = (c << 6) + lane;
      if (idx < (int)m) atomicAdd(&hist[w][sub][(cand[w][idx] >> shift) & 63u], 1u);
    }
    unsigned cnt = hist[w][0][lane] + hist[w][1][lane] + hist[w][2][lane] + hist[w][3][lane];
    unsigned incl = cnt;
#pragma unroll
    for (int off = 1; off < 64; off <<= 1) {
      unsigned t = __shfl_up(incl, off, 64);
      if (lane >= off) incl += t;
    }
    const unsigned excl = incl - cnt;
    const bool hit = (r >= excl) && (r < incl);
    const unsigned long long hm = __ballot(hit);
    const int Dp = __ffsll(hm) - 1;
    r -= __shfl(excl, Dp, 64);
    const unsigned m2 = __shfl(cnt, Dp, 64);
    // in-place compact (dest idx <= src idx; wave LDS ops in order)
    unsigned base = 0;
    for (int c = 0; c < nch; ++c) {
      const int idx = (c << 6) + lane;
      const bool va = idx < (int)m;
      const unsigned kk = va ? cand[w][idx] : 0u;
      const bool match = va && (((kk >> shift) & 63u) == (unsigned)Dp);
      const unsigned long long mk = __ballot(match);
      if (match) cand[w][base + (unsigned)__popcll(mk & ltm)] = kk;
      base += (unsigned)__popcll(mk);
    }
    m = m2;
  }

  // ---- finisher
  unsigned selKey = 0;
  bool win = false;
  if (m > 64u) {
    // exhausted all bits -> remaining candidates are identical keys
    selKey = cand[w][0];
    win = (lane == 0);
  } else {
    const unsigned myk = (lane < (int)m) ? cand[w][lane] : 0xFFFFFFFFu;
    unsigned cl = 0, ce = 0;
    for (int j = 0; j < (int)m; ++j) {
      const unsigned kj = cand[w][j];   // uniform addr -> LDS broadcast
      cl += (kj < myk) ? 1u : 0u;
      ce += (kj == myk) ? 1u : 0u;
    }
    selKey = myk;
    win = (lane < (int)m) && (cl <= r) && (r < cl + ce);
  }
  if (win) {
    const unsigned b = (selKey & 0x80000000u) ? (selKey & 0x7fffffffu) : ~selKey;
    med[row] = __uint_as_float(b);
  }
}

// ---------------- Kernel 2: small f32 GEMM out = med @ W^T + bias ------------
#define GO 32
#define GB 8
#define GK 64

__global__ __launch_bounds__(256) void gemm_kernel(
    const float* __restrict__ med, const float* __restrict__ W,
    const float* __restrict__ bias, float* __restrict__ out) {
  __shared__ float Ws[GK][GO + 1];  // [kc][ol], stride 33 -> conflict-free
  __shared__ float Ms[GB][GK];

  const int o0 = blockIdx.x * GO;
  const int b0 = blockIdx.y * GB;
  const int tid = threadIdx.x;
  const int to = tid & 31;
  const int tb = tid >> 5;

  float acc = 0.f;

  for (int k0 = 0; k0 < 768; k0 += GK) {
#pragma unroll
    for (int idx = tid; idx < GO * GK; idx += 256) {
      const int kc = idx & (GK - 1);
      const int ol = idx >> 6;
      const int o = o0 + ol;
      Ws[kc][ol] = (o < 1000) ? W[(size_t)o * 768 + k0 + kc] : 0.f;
    }
#pragma unroll
    for (int idx = tid; idx < GB * GK; idx += 256) {
      const int kc = idx & (GK - 1);
      const int bl = idx >> 6;
      Ms[bl][kc] = med[(size_t)(b0 + bl) * 768 + k0 + kc];
    }
    __syncthreads();
#pragma unroll
    for (int kk = 0; kk < GK; ++kk)
      acc = fmaf(Ms[tb][kk], Ws[kk][to], acc);
    __syncthreads();
  }

  const int o = o0 + to;
  if (o < 1000)
    out[(size_t)(b0 + tb) * 1000 + o] = acc + bias[o];
}

extern "C" void kernel_launch(void* const* d_in, const int* in_sizes, int n_in,
                              void* d_out, int out_size, void* d_ws, size_t ws_size,
                              hipStream_t stream) {
  const float* x = (const float*)d_in[0];    // [128,768,28,28]
  const float* W = (const float*)d_in[1];    // [1000,768]
  const float* b = (const float*)d_in[2];    // [1000]
  float* out = (float*)d_out;                // [128,1000]
  float* med = (float*)d_ws;                 // [128,768] scratch

  const int rows = 128 * 768;                // 98304
  kth_select_kernel<<<rows / NWAVE, 256, 0, stream>>>(x, med);

  dim3 grid((1000 + GO - 1) / GO, 128 / GB); // (32,16)
  gemm_kernel<<<grid, 256, 0, stream>>>(med, W, b, out);
}

// Round 4
// 125.473 us; speedup vs baseline: 2.9437x; 1.0205x over previous
//
#include <hip/hip_runtime.h>
#include <hip/hip_bf16.h>

// x[128][768][28][28] f32 -> per-(b,c) ascending-rank-392 of 784 values,
// then med[128][768] @ W[1000][768]^T + bias -> out[128][1000].

#define NROW 784
#define RANKK 392u
#define NWAVE 4   // rows (waves) per block

// ---------------- Kernel 1: per-wave exact select ----------------------------
// One 64-lane wave owns one row; no __syncthreads (wave-order LDS semantics).
// Pass 1 bins by monotone linear partition bucket = clamp(floor(32v)+32, 0,63)
// (low-conflict atomics; winning bucket m ~= 10 for this data), compacts the
// winning bucket via LDS atomic-append (order irrelevant for count-based
// finisher), then O(m) count-less-than finisher. Exact MSB 6-bit radix
// refinement remains as fallback for m > 64 (any data distribution).
__global__ __launch_bounds__(256) void kth_select_kernel(
    const float* __restrict__ x, float* __restrict__ med) {
  __shared__ unsigned cand[NWAVE][NROW];     // 12544 B
  __shared__ unsigned hist[NWAVE][4][65];    // 4160 B (stride 65 staggers banks)
  __shared__ unsigned apcnt[NWAVE];

  const int tid  = threadIdx.x;
  const int lane = tid & 63;
  const int w    = tid >> 6;
  const int row  = blockIdx.x * NWAVE + w;
  const float4* src4 = (const float4*)(x + (size_t)row * NROW);
  const int sub = lane & 3;

  // ---- load row: 196 float4 spread as {lane, 64+lane, 128+lane, 192+lane<4}
  float4 f0 = src4[lane];
  float4 f1 = src4[64 + lane];
  float4 f2 = src4[128 + lane];
  const bool v3 = (lane < 4);
  float4 f3 = make_float4(0.f, 0.f, 0.f, 0.f);
  if (v3) f3 = src4[192 + lane];

  const float vv[16] = {f0.x, f0.y, f0.z, f0.w, f1.x, f1.y, f1.z, f1.w,
                        f2.x, f2.y, f2.z, f2.w, f3.x, f3.y, f3.z, f3.w};

  // ---- monotone linear buckets: clamp(floor(32v)+32, 0, 63)
  // floor(32v)+32 == floor(fmaf(v,32,32)); saturating cvt handles overflow.
  int bkt[16];
#pragma unroll
  for (int j = 0; j < 16; ++j) {
    const int bi = __float2int_rd(fmaf(vv[j], 32.f, 32.f));
    bkt[j] = min(max(bi, 0), 63);
  }

  // ---- pass-1 histogram (4 bank-staggered sub-hists; wave-private, no sync)
#pragma unroll
  for (int s = 0; s < 4; ++s) hist[w][s][lane] = 0u;
  if (lane == 0) apcnt[w] = 0u;
#pragma unroll
  for (int j = 0; j < 12; ++j) atomicAdd(&hist[w][sub][bkt[j]], 1u);
  if (v3) {
#pragma unroll
    for (int j = 12; j < 16; ++j) atomicAdd(&hist[w][sub][bkt[j]], 1u);
  }

  unsigned r = RANKK;
  unsigned m;
  int D;
  {
    unsigned cnt = hist[w][0][lane] + hist[w][1][lane] + hist[w][2][lane] + hist[w][3][lane];
    unsigned incl = cnt;
#pragma unroll
    for (int off = 1; off < 64; off <<= 1) {
      unsigned t = __shfl_up(incl, off, 64);
      if (lane >= off) incl += t;
    }
    const unsigned excl = incl - cnt;
    const bool hit = (r >= excl) && (r < incl);
    const unsigned long long hm = __ballot(hit);
    D = __ffsll(hm) - 1;                // winning bucket == lane index
    r -= __shfl(excl, D, 64);
    m  = __shfl(cnt,  D, 64);
  }

  // ---- compact winning-bucket elements via atomic append (order irrelevant)
#pragma unroll
  for (int j = 0; j < 16; ++j) {
    const bool va = (j < 12) || v3;
    if (va && bkt[j] == D) {
      const unsigned b = __float_as_uint(vv[j]);
      const unsigned key = (b & 0x80000000u) ? ~b : (b | 0x80000000u);
      const unsigned slot = atomicAdd(&apcnt[w], 1u);
      cand[w][slot] = key;
    }
  }

  // ---- fallback: exact MSB 6-bit radix refinement (only if m > 64)
#pragma unroll 1
  for (int p = 0; p < 6; ++p) {
    if (m <= 64u) break;
    const int shift = (p < 5) ? (26 - 6 * p) : 0;
#pragma unroll
    for (int s = 0; s < 4; ++s) hist[w][s][lane] = 0u;
    const int nch = (int)((m + 63u) >> 6);
    for (int c = 0; c < nch; ++c) {
      const int idx = (c << 6) + lane;
      if (idx < (int)m) atomicAdd(&hist[w][sub][(cand[w][idx] >> shift) & 63u], 1u);
    }
    unsigned cnt = hist[w][0][lane] + hist[w][1][lane] + hist[w][2][lane] + hist[w][3][lane];
    unsigned incl = cnt;
#pragma unroll
    for (int off = 1; off < 64; off <<= 1) {
      unsigned t = __shfl_up(incl, off, 64);
      if (lane >= off) incl += t;
    }
    const unsigned excl = incl - cnt;
    const bool hit = (r >= excl) && (r < incl);
    const unsigned long long hm = __ballot(hit);
    const int Dp = __ffsll(hm) - 1;
    r -= __shfl(excl, Dp, 64);
    const unsigned m2 = __shfl(cnt, Dp, 64);
    // in-place compact via append: all lanes of a chunk read (one wave-wide
    // ds_read) before any write; total appends so far < next chunk's min read
    // index, so no unread slot is ever clobbered.
    if (lane == 0) apcnt[w] = 0u;
    for (int c = 0; c < nch; ++c) {
      const int idx = (c << 6) + lane;
      const bool va = idx < (int)m;
      const unsigned kk = va ? cand[w][idx] : 0u;
      if (va && (((kk >> shift) & 63u) == (unsigned)Dp)) {
        const unsigned slot = atomicAdd(&apcnt[w], 1u);
        cand[w][slot] = kk;
      }
    }
    m = m2;
  }

  // ---- finisher
  unsigned selKey = 0;
  bool win = false;
  if (m > 64u) {
    // exhausted all 32 key bits -> remaining candidates are identical
    selKey = cand[w][0];
    win = (lane == 0);
  } else {
    const unsigned myk = (lane < (int)m) ? cand[w][lane] : 0xFFFFFFFFu;
    unsigned cl = 0, ce = 0;
    for (int j = 0; j < (int)m; ++j) {
      const unsigned kj = cand[w][j];   // uniform addr -> LDS broadcast
      cl += (kj < myk) ? 1u : 0u;
      ce += (kj == myk) ? 1u : 0u;
    }
    selKey = myk;
    win = (lane < (int)m) && (cl <= r) && (r < cl + ce);
  }
  if (win) {
    const unsigned b = (selKey & 0x80000000u) ? (selKey & 0x7fffffffu) : ~selKey;
    med[row] = __uint_as_float(b);
  }
}

// ---------------- Kernel 2: small f32 GEMM out = med @ W^T + bias ------------
#define GO 32
#define GB 16
#define GK 64

__global__ __launch_bounds__(256) void gemm_kernel(
    const float* __restrict__ med, const float* __restrict__ W,
    const float* __restrict__ bias, float* __restrict__ out) {
  __shared__ float Ws[GK][GO + 1];  // [kc][ol], stride 33 -> conflict-free
  __shared__ float Ms[GB][GK];

  const int o0 = blockIdx.x * GO;
  const int b0 = blockIdx.y * GB;
  const int tid = threadIdx.x;
  const int to = tid & 31;
  const int tb = tid >> 5;   // 0..7, two b's each

  float acc0 = 0.f, acc1 = 0.f;

  for (int k0 = 0; k0 < 768; k0 += GK) {
#pragma unroll
    for (int idx = tid; idx < GO * GK; idx += 256) {
      const int kc = idx & (GK - 1);
      const int ol = idx >> 6;
      const int o = o0 + ol;
      Ws[kc][ol] = (o < 1000) ? W[(size_t)o * 768 + k0 + kc] : 0.f;
    }
#pragma unroll
    for (int idx = tid; idx < GB * GK; idx += 256) {
      const int kc = idx & (GK - 1);
      const int bl = idx >> 6;
      Ms[bl][kc] = med[(size_t)(b0 + bl) * 768 + k0 + kc];
    }
    __syncthreads();

    const int bl = tb * 2;
#pragma unroll
    for (int kk = 0; kk < GK; ++kk) {
      const float wv = Ws[kk][to];
      acc0 = fmaf(Ms[bl][kk], wv, acc0);
      acc1 = fmaf(Ms[bl + 1][kk], wv, acc1);
    }
    __syncthreads();
  }

  const int o = o0 + to;
  if (o < 1000) {
    const float bb = bias[o];
    const int b = b0 + tb * 2;
    out[(size_t)b * 1000 + o] = acc0 + bb;
    out[(size_t)(b + 1) * 1000 + o] = acc1 + bb;
  }
}

extern "C" void kernel_launch(void* const* d_in, const int* in_sizes, int n_in,
                              void* d_out, int out_size, void* d_ws, size_t ws_size,
                              hipStream_t stream) {
  const float* x = (const float*)d_in[0];    // [128,768,28,28]
  const float* W = (const float*)d_in[1];    // [1000,768]
  const float* b = (const float*)d_in[2];    // [1000]
  float* out = (float*)d_out;                // [128,1000]
  float* med = (float*)d_ws;                 // [128,768] scratch

  const int rows = 128 * 768;                // 98304
  kth_select_kernel<<<rows / NWAVE, 256, 0, stream>>>(x, med);

  dim3 grid((1000 + GO - 1) / GO, 128 / GB); // (32, 8)
  gemm_kernel<<<grid, 256, 0, stream>>>(med, W, b, out);
}